// Round 2
// baseline (561.080 us; speedup 1.0000x reference)
//
#include <hip/hip_runtime.h>
#include <math.h>

// Problem constants (fixed by the reference).
#define KCODES 512
#define DDIM   64
#define NROWS  262144

// ---------------------------------------------------------------------------
// Bit-exact replication of the harness's numpy fp32 reference:
//   c_sqr = np.sum(c*c, axis=1)            (pairwise, 8-acc stride-8, n=64)
//   x_sqr = np.sum(x*x, axis=1)            (same)
//   mm    = x @ c.T                        (OpenBLAS sgemm: sequential FMA
//                                           chain over k=0..63, start 0)
//   d     = fl( fl(x_sqr + c_sqr) - 2*mm ) (2*mm exact)
//   argmin, first occurrence
// All critical ops via __fadd_rn/__fmul_rn/__fmaf_rn so the compiler cannot
// contract or reassociate. GPU fp32 RNE == x86 fp32 RNE -> bit-exact.
// ---------------------------------------------------------------------------

// numpy pairwise_sum base case for n=64: element a_i = fl(v_i * v_i);
// r[j] = a[j] + a[j+8] + ... + a[j+56] (sequential adds);
// result = ((r0+r1)+(r2+r3)) + ((r4+r5)+(r6+r7)).
__device__ __forceinline__ float np_sumsq64(const float* v) {
    float r[8];
#pragma unroll
    for (int j = 0; j < 8; ++j) r[j] = __fmul_rn(v[j], v[j]);
#pragma unroll
    for (int i = 8; i < 64; i += 8) {
#pragma unroll
        for (int j = 0; j < 8; ++j)
            r[j] = __fadd_rn(r[j], __fmul_rn(v[i + j], v[i + j]));
    }
    float t01 = __fadd_rn(r[0], r[1]);
    float t23 = __fadd_rn(r[2], r[3]);
    float t45 = __fadd_rn(r[4], r[5]);
    float t67 = __fadd_rn(r[6], r[7]);
    return __fadd_rn(__fadd_rn(t01, t23), __fadd_rn(t45, t67));
}

// Kernel 1: cs[k] = numpy-exact c_sqr.
__global__ void vq_prep(const float* __restrict__ cb, float* __restrict__ cs) {
    int k = blockIdx.x * blockDim.x + threadIdx.x;
    if (k < KCODES) {
        float v[DDIM];
        const float4* c4 = (const float4*)(cb + (size_t)k * DDIM);
#pragma unroll
        for (int i = 0; i < DDIM / 4; ++i) {
            float4 t = c4[i];
            v[4 * i + 0] = t.x; v[4 * i + 1] = t.y;
            v[4 * i + 2] = t.z; v[4 * i + 3] = t.w;
        }
        cs[k] = np_sumsq64(v);
    }
}

// Kernel 2: one thread per row; row x in VGPRs; wave-uniform codebook
// address -> scalar loads. k unrolled x2 for two independent FMA chains.
__launch_bounds__(256)
__global__ void vq_main(const float* __restrict__ x,
                        const float* __restrict__ cb,
                        const float* __restrict__ cs,
                        float* __restrict__ out) {
    const int r = blockIdx.x * blockDim.x + threadIdx.x;

    float xa[DDIM];
    const float4* xr = (const float4*)(x + (size_t)r * DDIM);
#pragma unroll
    for (int i = 0; i < DDIM / 4; ++i) {
        float4 t = xr[i];
        xa[4 * i + 0] = t.x; xa[4 * i + 1] = t.y;
        xa[4 * i + 2] = t.z; xa[4 * i + 3] = t.w;
    }

    const float xs = np_sumsq64(xa);

    float best = INFINITY;
    int bi = 0;

    for (int k = 0; k < KCODES; k += 2) {
        const float* c0 = cb + (size_t)k * DDIM;        // wave-uniform
        const float* c1 = c0 + DDIM;
        float a0 = 0.f, a1 = 0.f;                       // sequential chains
#pragma unroll
        for (int i = 0; i < DDIM; ++i) {
            a0 = __fmaf_rn(xa[i], c0[i], a0);
            a1 = __fmaf_rn(xa[i], c1[i], a1);
        }
        // d = fl( fl(xs + cs_k) - 2*mm );  (-2*mm exact)
        float d0 = __fadd_rn(__fadd_rn(xs, cs[k]),     __fmul_rn(-2.0f, a0));
        float d1 = __fadd_rn(__fadd_rn(xs, cs[k + 1]), __fmul_rn(-2.0f, a1));
        // strict '<' ascending k == numpy first-occurrence argmin
        if (d0 < best) { best = d0; bi = k; }
        if (d1 < best) { best = d1; bi = k + 1; }
    }

    // Epilogue: z_q_x = z_q_x_bar = codebook[bi] (bit-exact copy); index.
    const float4* cq = (const float4*)(cb + (size_t)bi * DDIM);
    float4* o0 = (float4*)(out + (size_t)r * DDIM);
    float4* o1 = (float4*)(out + (size_t)NROWS * DDIM + (size_t)r * DDIM);
#pragma unroll
    for (int i = 0; i < DDIM / 4; ++i) {
        float4 v = cq[i];
        o0[i] = v;
        o1[i] = v;
    }
    out[(size_t)2 * NROWS * DDIM + (size_t)r] = (float)bi;
}

extern "C" void kernel_launch(void* const* d_in, const int* in_sizes, int n_in,
                              void* d_out, int out_size, void* d_ws, size_t ws_size,
                              hipStream_t stream) {
    const float* z  = (const float*)d_in[0];   // [N, D] fp32
    const float* cb = (const float*)d_in[1];   // [K, D] fp32
    float* out = (float*)d_out;                // [N*D | N*D | N] fp32
    float* cs  = (float*)d_ws;                 // 512 floats scratch

    vq_prep<<<2, 256, 0, stream>>>(cb, cs);
    vq_main<<<NROWS / 256, 256, 0, stream>>>(z, cb, cs, out);
}

// Round 3
// 529.829 us; speedup vs baseline: 1.0590x; 1.0590x over previous
//
#include <hip/hip_runtime.h>
#include <math.h>

// Problem constants (fixed by the reference).
#define KCODES 512
#define DDIM   64
#define NROWS  262144

// ---------------------------------------------------------------------------
// Bit-exact replication of the harness's numpy fp32 reference (verified R2,
// absmax=0):
//   c_sqr = np.sum(c*c, axis=1)            (pairwise, 8-acc stride-8, n=64)
//   x_sqr = np.sum(x*x, axis=1)            (same)
//   mm    = x @ c.T                        (OpenBLAS sgemm: sequential FMA
//                                           chain over k=0..63, start 0)
//   d     = fl( fl(x_sqr + c_sqr) - 2*mm ) (2*mm exact)
//   argmin, first occurrence
// All critical ops via __fadd_rn/__fmul_rn/__fmaf_rn so the compiler cannot
// contract or reassociate. GPU fp32 RNE == x86 fp32 RNE -> bit-exact.
//
// R3 change: performance only — __launch_bounds__(256,4) so the 64-float row
// stays in VGPRs (R2's build chose 40 VGPRs and spilled the row to scratch:
// VALUBusy 54%, 455us). k-loop widened to 4 independent FMA chains.
// ---------------------------------------------------------------------------

// numpy pairwise_sum base case for n=64.
__device__ __forceinline__ float np_sumsq64(const float* v) {
    float r[8];
#pragma unroll
    for (int j = 0; j < 8; ++j) r[j] = __fmul_rn(v[j], v[j]);
#pragma unroll
    for (int i = 8; i < 64; i += 8) {
#pragma unroll
        for (int j = 0; j < 8; ++j)
            r[j] = __fadd_rn(r[j], __fmul_rn(v[i + j], v[i + j]));
    }
    float t01 = __fadd_rn(r[0], r[1]);
    float t23 = __fadd_rn(r[2], r[3]);
    float t45 = __fadd_rn(r[4], r[5]);
    float t67 = __fadd_rn(r[6], r[7]);
    return __fadd_rn(__fadd_rn(t01, t23), __fadd_rn(t45, t67));
}

// Kernel 1: cs[k] = numpy-exact c_sqr.
__global__ void vq_prep(const float* __restrict__ cb, float* __restrict__ cs) {
    int k = blockIdx.x * blockDim.x + threadIdx.x;
    if (k < KCODES) {
        float v[DDIM];
        const float4* c4 = (const float4*)(cb + (size_t)k * DDIM);
#pragma unroll
        for (int i = 0; i < DDIM / 4; ++i) {
            float4 t = c4[i];
            v[4 * i + 0] = t.x; v[4 * i + 1] = t.y;
            v[4 * i + 2] = t.z; v[4 * i + 3] = t.w;
        }
        cs[k] = np_sumsq64(v);
    }
}

// Kernel 2: one thread per row; row x in VGPRs (forced by launch bounds);
// wave-uniform codebook address -> s_load SGPR broadcast into v_fmac.
// 4 independent sequential chains hide FMA latency.
__launch_bounds__(256, 4)  // <=128 VGPR: row (64) + chains + addr, no spill
__global__ void vq_main(const float* __restrict__ x,
                        const float* __restrict__ cb,
                        const float* __restrict__ cs,
                        float* __restrict__ out) {
    const int r = blockIdx.x * blockDim.x + threadIdx.x;

    float xa[DDIM];
    const float4* xr = (const float4*)(x + (size_t)r * DDIM);
#pragma unroll
    for (int i = 0; i < DDIM / 4; ++i) {
        float4 t = xr[i];
        xa[4 * i + 0] = t.x; xa[4 * i + 1] = t.y;
        xa[4 * i + 2] = t.z; xa[4 * i + 3] = t.w;
    }

    const float xs = np_sumsq64(xa);

    float best = INFINITY;
    int bi = 0;

    for (int k = 0; k < KCODES; k += 4) {
        const float* c0 = cb + (size_t)k * DDIM;        // wave-uniform
        const float* c1 = c0 + DDIM;
        const float* c2 = c0 + 2 * DDIM;
        const float* c3 = c0 + 3 * DDIM;
        float a0 = 0.f, a1 = 0.f, a2 = 0.f, a3 = 0.f;   // sequential chains
#pragma unroll
        for (int i = 0; i < DDIM; ++i) {
            a0 = __fmaf_rn(xa[i], c0[i], a0);
            a1 = __fmaf_rn(xa[i], c1[i], a1);
            a2 = __fmaf_rn(xa[i], c2[i], a2);
            a3 = __fmaf_rn(xa[i], c3[i], a3);
        }
        // d = fl( fl(xs + cs_k) - 2*mm );  (-2*mm exact)
        float d0 = __fadd_rn(__fadd_rn(xs, cs[k + 0]), __fmul_rn(-2.0f, a0));
        float d1 = __fadd_rn(__fadd_rn(xs, cs[k + 1]), __fmul_rn(-2.0f, a1));
        float d2 = __fadd_rn(__fadd_rn(xs, cs[k + 2]), __fmul_rn(-2.0f, a2));
        float d3 = __fadd_rn(__fadd_rn(xs, cs[k + 3]), __fmul_rn(-2.0f, a3));
        // strict '<' ascending k == numpy first-occurrence argmin
        if (d0 < best) { best = d0; bi = k + 0; }
        if (d1 < best) { best = d1; bi = k + 1; }
        if (d2 < best) { best = d2; bi = k + 2; }
        if (d3 < best) { best = d3; bi = k + 3; }
    }

    // Epilogue: z_q_x = z_q_x_bar = codebook[bi] (bit-exact copy); index.
    const float4* cq = (const float4*)(cb + (size_t)bi * DDIM);
    float4* o0 = (float4*)(out + (size_t)r * DDIM);
    float4* o1 = (float4*)(out + (size_t)NROWS * DDIM + (size_t)r * DDIM);
#pragma unroll
    for (int i = 0; i < DDIM / 4; ++i) {
        float4 v = cq[i];
        o0[i] = v;
        o1[i] = v;
    }
    out[(size_t)2 * NROWS * DDIM + (size_t)r] = (float)bi;
}

extern "C" void kernel_launch(void* const* d_in, const int* in_sizes, int n_in,
                              void* d_out, int out_size, void* d_ws, size_t ws_size,
                              hipStream_t stream) {
    const float* z  = (const float*)d_in[0];   // [N, D] fp32
    const float* cb = (const float*)d_in[1];   // [K, D] fp32
    float* out = (float*)d_out;                // [N*D | N*D | N] fp32
    float* cs  = (float*)d_ws;                 // 512 floats scratch

    vq_prep<<<2, 256, 0, stream>>>(cb, cs);
    vq_main<<<NROWS / 256, 256, 0, stream>>>(z, cb, cs, out);
}

// Round 4
// 515.722 us; speedup vs baseline: 1.0880x; 1.0274x over previous
//
#include <hip/hip_runtime.h>
#include <math.h>

// Problem constants (fixed by the reference).
#define KCODES 512
#define DDIM   64
#define NROWS  262144

// ---------------------------------------------------------------------------
// Bit-exact replication of the harness's numpy fp32 reference (verified R2,
// absmax=0):
//   c_sqr = np.sum(c*c, axis=1)            (pairwise, 8-acc stride-8, n=64)
//   x_sqr = np.sum(x*x, axis=1)            (same)
//   mm    = x @ c.T                        (sequential FMA chain k=0..63, from 0)
//   d     = fl( fl(x_sqr + c_sqr) - 2*mm ) (2*mm exact)
//   argmin, first occurrence (strict '<', ascending k)
//
// R4 change (perf only; arithmetic identical): R2/R3 disas evidence
// (VGPR=40, VALUBusy 55-58%, 428us vs 109us FMA floor) says the i-loop never
// unrolled -> xa[] stayed addressable (scratch / re-load per use). This
// version has NO addressable array: 64 named floats, inline-asm pinned to
// VGPRs, dot products macro-unrolled with literal indices. 2 codes per
// k-iteration = 2 independent sequential FMA chains.
// ---------------------------------------------------------------------------

// numpy pairwise_sum base case for n=64 (pointer version, used by vq_prep).
__device__ __forceinline__ float np_sumsq64(const float* v) {
    float r[8];
#pragma unroll
    for (int j = 0; j < 8; ++j) r[j] = __fmul_rn(v[j], v[j]);
#pragma unroll
    for (int i = 8; i < 64; i += 8) {
#pragma unroll
        for (int j = 0; j < 8; ++j)
            r[j] = __fadd_rn(r[j], __fmul_rn(v[i + j], v[i + j]));
    }
    float t01 = __fadd_rn(r[0], r[1]);
    float t23 = __fadd_rn(r[2], r[3]);
    float t45 = __fadd_rn(r[4], r[5]);
    float t67 = __fadd_rn(r[6], r[7]);
    return __fadd_rn(__fadd_rn(t01, t23), __fadd_rn(t45, t67));
}

// Kernel 1: cs[k] = numpy-exact c_sqr. Tiny (512 rows), runs once.
__global__ void vq_prep(const float* __restrict__ cb, float* __restrict__ cs) {
    int k = blockIdx.x * blockDim.x + threadIdx.x;
    if (k < KCODES) {
        float v[DDIM];
        const float4* c4 = (const float4*)(cb + (size_t)k * DDIM);
#pragma unroll
        for (int i = 0; i < DDIM / 4; ++i) {
            float4 t = c4[i];
            v[4 * i + 0] = t.x; v[4 * i + 1] = t.y;
            v[4 * i + 2] = t.z; v[4 * i + 3] = t.w;
        }
        cs[k] = np_sumsq64(v);
    }
}

// --- macro helpers (literal indices only; nothing addressable) -------------
#define LD4(n, t) float x##n = t.x; float CAT1(x, n, 1) = t.y;
// token-paste helpers won't do arithmetic; list components explicitly instead.

__launch_bounds__(256, 4)
__global__ void vq_main(const float* __restrict__ x,
                        const float* __restrict__ cb,
                        const float* __restrict__ cs,
                        float* __restrict__ out) {
    const int r = blockIdx.x * blockDim.x + threadIdx.x;
    const float4* xr = (const float4*)(x + (size_t)r * DDIM);

    // 64 named floats; no array, no loop over them.
    float4 t;
    t = xr[0];  float x0 = t.x, x1 = t.y, x2 = t.z, x3 = t.w;
    t = xr[1];  float x4 = t.x, x5 = t.y, x6 = t.z, x7 = t.w;
    t = xr[2];  float x8 = t.x, x9 = t.y, x10 = t.z, x11 = t.w;
    t = xr[3];  float x12 = t.x, x13 = t.y, x14 = t.z, x15 = t.w;
    t = xr[4];  float x16 = t.x, x17 = t.y, x18 = t.z, x19 = t.w;
    t = xr[5];  float x20 = t.x, x21 = t.y, x22 = t.z, x23 = t.w;
    t = xr[6];  float x24 = t.x, x25 = t.y, x26 = t.z, x27 = t.w;
    t = xr[7];  float x28 = t.x, x29 = t.y, x30 = t.z, x31 = t.w;
    t = xr[8];  float x32 = t.x, x33 = t.y, x34 = t.z, x35 = t.w;
    t = xr[9];  float x36 = t.x, x37 = t.y, x38 = t.z, x39 = t.w;
    t = xr[10]; float x40 = t.x, x41 = t.y, x42 = t.z, x43 = t.w;
    t = xr[11]; float x44 = t.x, x45 = t.y, x46 = t.z, x47 = t.w;
    t = xr[12]; float x48 = t.x, x49 = t.y, x50 = t.z, x51 = t.w;
    t = xr[13]; float x52 = t.x, x53 = t.y, x54 = t.z, x55 = t.w;
    t = xr[14]; float x56 = t.x, x57 = t.y, x58 = t.z, x59 = t.w;
    t = xr[15]; float x60 = t.x, x61 = t.y, x62 = t.z, x63 = t.w;

    // Pin to VGPRs: blocks rematerialization-by-reload and folds.
#define PIN4(a, b, c, d) asm volatile("" : "+v"(a), "+v"(b), "+v"(c), "+v"(d));
    PIN4(x0, x1, x2, x3)     PIN4(x4, x5, x6, x7)
    PIN4(x8, x9, x10, x11)   PIN4(x12, x13, x14, x15)
    PIN4(x16, x17, x18, x19) PIN4(x20, x21, x22, x23)
    PIN4(x24, x25, x26, x27) PIN4(x28, x29, x30, x31)
    PIN4(x32, x33, x34, x35) PIN4(x36, x37, x38, x39)
    PIN4(x40, x41, x42, x43) PIN4(x44, x45, x46, x47)
    PIN4(x48, x49, x50, x51) PIN4(x52, x53, x54, x55)
    PIN4(x56, x57, x58, x59) PIN4(x60, x61, x62, x63)
#undef PIN4

    // xs = numpy-exact sum(x*x): 8 accumulators stride-8, sequential adds,
    // pairwise combine. Manually unrolled, literal names.
#define ACC(rj, v) rj = __fadd_rn(rj, __fmul_rn(v, v));
    float r0 = __fmul_rn(x0, x0);
    ACC(r0, x8)  ACC(r0, x16) ACC(r0, x24) ACC(r0, x32) ACC(r0, x40) ACC(r0, x48) ACC(r0, x56)
    float r1 = __fmul_rn(x1, x1);
    ACC(r1, x9)  ACC(r1, x17) ACC(r1, x25) ACC(r1, x33) ACC(r1, x41) ACC(r1, x49) ACC(r1, x57)
    float r2 = __fmul_rn(x2, x2);
    ACC(r2, x10) ACC(r2, x18) ACC(r2, x26) ACC(r2, x34) ACC(r2, x42) ACC(r2, x50) ACC(r2, x58)
    float r3 = __fmul_rn(x3, x3);
    ACC(r3, x11) ACC(r3, x19) ACC(r3, x27) ACC(r3, x35) ACC(r3, x43) ACC(r3, x51) ACC(r3, x59)
    float r4 = __fmul_rn(x4, x4);
    ACC(r4, x12) ACC(r4, x20) ACC(r4, x28) ACC(r4, x36) ACC(r4, x44) ACC(r4, x52) ACC(r4, x60)
    float r5 = __fmul_rn(x5, x5);
    ACC(r5, x13) ACC(r5, x21) ACC(r5, x29) ACC(r5, x37) ACC(r5, x45) ACC(r5, x53) ACC(r5, x61)
    float r6 = __fmul_rn(x6, x6);
    ACC(r6, x14) ACC(r6, x22) ACC(r6, x30) ACC(r6, x38) ACC(r6, x46) ACC(r6, x54) ACC(r6, x62)
    float r7 = __fmul_rn(x7, x7);
    ACC(r7, x15) ACC(r7, x23) ACC(r7, x31) ACC(r7, x39) ACC(r7, x47) ACC(r7, x55) ACC(r7, x63)
#undef ACC
    const float xs = __fadd_rn(__fadd_rn(__fadd_rn(r0, r1), __fadd_rn(r2, r3)),
                               __fadd_rn(__fadd_rn(r4, r5), __fadd_rn(r6, r7)));

    float best = INFINITY;
    int bi = 0;

#pragma unroll 1
    for (int k = 0; k < KCODES; k += 2) {
        const float* c0 = cb + (size_t)k * DDIM;  // wave-uniform -> s_load
        const float* c1 = c0 + DDIM;
        float a0 = 0.f, a1 = 0.f;                 // 2 sequential chains
#define STEP(i) a0 = __fmaf_rn(x##i, c0[i], a0); a1 = __fmaf_rn(x##i, c1[i], a1);
        STEP(0)  STEP(1)  STEP(2)  STEP(3)  STEP(4)  STEP(5)  STEP(6)  STEP(7)
        STEP(8)  STEP(9)  STEP(10) STEP(11) STEP(12) STEP(13) STEP(14) STEP(15)
        STEP(16) STEP(17) STEP(18) STEP(19) STEP(20) STEP(21) STEP(22) STEP(23)
        STEP(24) STEP(25) STEP(26) STEP(27) STEP(28) STEP(29) STEP(30) STEP(31)
        STEP(32) STEP(33) STEP(34) STEP(35) STEP(36) STEP(37) STEP(38) STEP(39)
        STEP(40) STEP(41) STEP(42) STEP(43) STEP(44) STEP(45) STEP(46) STEP(47)
        STEP(48) STEP(49) STEP(50) STEP(51) STEP(52) STEP(53) STEP(54) STEP(55)
        STEP(56) STEP(57) STEP(58) STEP(59) STEP(60) STEP(61) STEP(62) STEP(63)
#undef STEP
        // d = fl( fl(xs + cs_k) - 2*mm );  (-2*mm exact, power of 2)
        float d0 = __fadd_rn(__fadd_rn(xs, cs[k + 0]), __fmul_rn(-2.0f, a0));
        float d1 = __fadd_rn(__fadd_rn(xs, cs[k + 1]), __fmul_rn(-2.0f, a1));
        // strict '<' ascending k == numpy first-occurrence argmin
        if (d0 < best) { best = d0; bi = k + 0; }
        if (d1 < best) { best = d1; bi = k + 1; }
    }

    // Epilogue: z_q_x = z_q_x_bar = codebook[bi] (bit-exact copy); index.
    const float4* cq = (const float4*)(cb + (size_t)bi * DDIM);
    float4* o0 = (float4*)(out + (size_t)r * DDIM);
    float4* o1 = (float4*)(out + (size_t)NROWS * DDIM + (size_t)r * DDIM);
#pragma unroll
    for (int i = 0; i < DDIM / 4; ++i) {
        float4 v = cq[i];
        o0[i] = v;
        o1[i] = v;
    }
    out[(size_t)2 * NROWS * DDIM + (size_t)r] = (float)bi;
}

extern "C" void kernel_launch(void* const* d_in, const int* in_sizes, int n_in,
                              void* d_out, int out_size, void* d_ws, size_t ws_size,
                              hipStream_t stream) {
    const float* z  = (const float*)d_in[0];   // [N, D] fp32
    const float* cb = (const float*)d_in[1];   // [K, D] fp32
    float* out = (float*)d_out;                // [N*D | N*D | N] fp32
    float* cs  = (float*)d_ws;                 // 512 floats scratch

    vq_prep<<<2, 256, 0, stream>>>(cb, cs);
    vq_main<<<NROWS / 256, 256, 0, stream>>>(z, cb, cs, out);
}

// Round 5
// 445.143 us; speedup vs baseline: 1.2605x; 1.1586x over previous
//
#include <hip/hip_runtime.h>
#include <math.h>

// Problem constants (fixed by the reference).
#define KCODES 512
#define DDIM   64
#define NROWS  262144
#define ND     ((size_t)NROWS * DDIM)
#define MBLK   64            // rows per block
#define MARGIN 1.5e-4f       // rigorous exclusion margin (see header comment)

// ---------------------------------------------------------------------------
// Architecture (R5):
//  * prep:  numpy-exact c_sqr (verified R2) + bf16 hi/lo split of codebook.
//  * main:  per 64-row block, MFMA filter g(k) = c_sqr[k] - 2*x.c[k] using
//           bf16 hi/lo of x and c (terms xh*ch + xl*ch + xh*cl; lo*lo term
//           dropped).  Rigorous |g_filter - g_true| <= 2*(2^-16*S + resid +
//           accum) ~ 2.4e-5 with S = max Sum|x_i||c_i| <= 0.2.  Reference's
//           own fp32 rounding eta <= 3.3e-5 (values < 128, ulp 1.53e-5 x2).
//           M = 1.5e-4 > 2*eta + 2*g_err  =>  any k with filter score >
//           rowmin + M provably cannot be the numpy argmin.
//  * scores stored fp32 in LDS; candidates within M collected; 1 candidate
//    -> winner; >=2 -> bit-exact numpy-replica evaluation (verified R2:
//    sequential-FMA mm chain, pairwise sumsq, fl(fl(xs+cs)-2mm), strict '<'
//    first-occurrence).  Capacity-8 list; overflow -> exact scan of all 512.
// ---------------------------------------------------------------------------

typedef __attribute__((ext_vector_type(8))) short s16x8;
typedef __attribute__((ext_vector_type(4))) float f32x4;
union U4S8 { uint4 u; s16x8 s; };

__device__ __forceinline__ unsigned short bf16_rne(float f) {
    unsigned u = __float_as_uint(f);
    return (unsigned short)((u + 0x7FFFu + ((u >> 16) & 1u)) >> 16);
}
__device__ __forceinline__ float bf16_tof(unsigned short h) {
    return __uint_as_float(((unsigned)h) << 16);
}

// numpy pairwise_sum base case for n=64 (verified bit-exact in R2).
__device__ __forceinline__ float np_sumsq64(const float* v) {
    float r[8];
#pragma unroll
    for (int j = 0; j < 8; ++j) r[j] = __fmul_rn(v[j], v[j]);
#pragma unroll
    for (int i = 8; i < 64; i += 8) {
#pragma unroll
        for (int j = 0; j < 8; ++j)
            r[j] = __fadd_rn(r[j], __fmul_rn(v[i + j], v[i + j]));
    }
    float t01 = __fadd_rn(r[0], r[1]);
    float t23 = __fadd_rn(r[2], r[3]);
    float t45 = __fadd_rn(r[4], r[5]);
    float t67 = __fadd_rn(r[6], r[7]);
    return __fadd_rn(__fadd_rn(t01, t23), __fadd_rn(t45, t67));
}

// Prep: cs[k] = numpy-exact c_sqr; cbh/cbl = bf16 hi/lo split of codebook.
__global__ void vq_prep(const float* __restrict__ cb, float* __restrict__ cs,
                        unsigned short* __restrict__ cbh,
                        unsigned short* __restrict__ cbl) {
    int k = blockIdx.x * blockDim.x + threadIdx.x;
    if (k < KCODES) {
        float v[DDIM];
        const float4* c4 = (const float4*)(cb + (size_t)k * DDIM);
#pragma unroll
        for (int i = 0; i < DDIM / 4; ++i) {
            float4 t = c4[i];
            v[4 * i + 0] = t.x; v[4 * i + 1] = t.y;
            v[4 * i + 2] = t.z; v[4 * i + 3] = t.w;
        }
        cs[k] = np_sumsq64(v);
#pragma unroll
        for (int i = 0; i < DDIM; ++i) {
            unsigned short h = bf16_rne(v[i]);
            cbh[(size_t)k * DDIM + i] = h;
            cbl[(size_t)k * DDIM + i] = bf16_rne(v[i] - bf16_tof(h));
        }
    }
}

__device__ __forceinline__ void pack8(float4 a, float4 b, uint4& hi, uint4& lo) {
    unsigned short h0 = bf16_rne(a.x), h1 = bf16_rne(a.y),
                   h2 = bf16_rne(a.z), h3 = bf16_rne(a.w);
    unsigned short h4 = bf16_rne(b.x), h5 = bf16_rne(b.y),
                   h6 = bf16_rne(b.z), h7 = bf16_rne(b.w);
    unsigned short l0 = bf16_rne(a.x - bf16_tof(h0)), l1 = bf16_rne(a.y - bf16_tof(h1)),
                   l2 = bf16_rne(a.z - bf16_tof(h2)), l3 = bf16_rne(a.w - bf16_tof(h3));
    unsigned short l4 = bf16_rne(b.x - bf16_tof(h4)), l5 = bf16_rne(b.y - bf16_tof(h5)),
                   l6 = bf16_rne(b.z - bf16_tof(h6)), l7 = bf16_rne(b.w - bf16_tof(h7));
    hi.x = (unsigned)h0 | ((unsigned)h1 << 16); hi.y = (unsigned)h2 | ((unsigned)h3 << 16);
    hi.z = (unsigned)h4 | ((unsigned)h5 << 16); hi.w = (unsigned)h6 | ((unsigned)h7 << 16);
    lo.x = (unsigned)l0 | ((unsigned)l1 << 16); lo.y = (unsigned)l2 | ((unsigned)l3 << 16);
    lo.z = (unsigned)l4 | ((unsigned)l5 << 16); lo.w = (unsigned)l6 | ((unsigned)l7 << 16);
}

// Bit-exact numpy-replica selection among candidate codes (verified R2).
__device__ int exact_select(const float* __restrict__ x, const float* __restrict__ cb,
                            const float* csl, int grow, const int* cand, int nc) {
    float v[DDIM];
    const float4* xr = (const float4*)(x + (size_t)grow * DDIM);
#pragma unroll
    for (int i = 0; i < 16; ++i) {
        float4 tv = xr[i];
        v[4*i] = tv.x; v[4*i+1] = tv.y; v[4*i+2] = tv.z; v[4*i+3] = tv.w;
    }
    float xs = np_sumsq64(v);
    float db = INFINITY; int kb = 0x7fffffff;
    for (int j = 0; j < nc; ++j) {
        int k = cand[j];
        const float* c = cb + (size_t)k * DDIM;
        float a = 0.f;
#pragma unroll
        for (int i = 0; i < DDIM; ++i) a = __fmaf_rn(v[i], c[i], a);
        float d = __fadd_rn(__fadd_rn(xs, csl[k]), __fmul_rn(-2.0f, a));
        if (d < db || (d == db && k < kb)) { db = d; kb = k; }
    }
    return kb;
}
__device__ int exact_select_all(const float* __restrict__ x, const float* __restrict__ cb,
                                const float* csl, int grow) {
    float v[DDIM];
    const float4* xr = (const float4*)(x + (size_t)grow * DDIM);
#pragma unroll
    for (int i = 0; i < 16; ++i) {
        float4 tv = xr[i];
        v[4*i] = tv.x; v[4*i+1] = tv.y; v[4*i+2] = tv.z; v[4*i+3] = tv.w;
    }
    float xs = np_sumsq64(v);
    float db = INFINITY; int kb = 0;
    for (int k = 0; k < KCODES; ++k) {     // ascending + strict '<' = first occ.
        const float* c = cb + (size_t)k * DDIM;
        float a = 0.f;
#pragma unroll
        for (int i = 0; i < DDIM; ++i) a = __fmaf_rn(v[i], c[i], a);
        float d = __fadd_rn(__fadd_rn(xs, csl[k]), __fmul_rn(-2.0f, a));
        if (d < db) { db = d; kb = k; }
    }
    return kb;
}

// Dynamic-LDS layout (bytes):
//   chL    @      0  (32768)   bf16-hi B tile, 256 codes, swizzled 16B granules
//   clL    @  32768  (32768)   bf16-lo
//   sc     @  65536  (65792)   fp32 scores [64 rows][257]
//   csl    @ 131328  ( 2048)   c_sqr all 512
//   segmn  @ 133376  ( 1024)   [4 seg][64 row]
//   rowmn  @ 134400  (  256)
//   cnt    @ 134656  (  256)
//   lstk   @ 134912  ( 2048)   [64][8] candidate k
//   lsts   @ 136960  ( 2048)   [64][8] candidate score
//   win    @ 139008  (  256)
#define SMEM_BYTES 139264

__launch_bounds__(256, 1)
__global__ void vq_main(const float* __restrict__ x, const float* __restrict__ cb,
                        const float* __restrict__ cs,
                        const unsigned short* __restrict__ cbh,
                        const unsigned short* __restrict__ cbl,
                        float* __restrict__ out) {
    extern __shared__ char smem[];
    uint4* chL   = (uint4*)(smem);
    uint4* clL   = (uint4*)(smem + 32768);
    float* sc    = (float*)(smem + 65536);
    float* csl   = (float*)(smem + 131328);
    float* segmn = (float*)(smem + 133376);
    float* rowmn = (float*)(smem + 134400);
    int*   cnt   = (int*)  (smem + 134656);
    int*   lstk  = (int*)  (smem + 134912);
    float* lsts  = (float*)(smem + 136960);
    int*   win   = (int*)  (smem + 139008);

    const int t    = threadIdx.x;
    const int ln   = t & 63;
    const int wv   = t >> 6;
    const int m    = ln & 15;
    const int quad = ln >> 4;
    const int rowBlk0 = blockIdx.x * MBLK;

    if (t < 64) { rowmn[t] = INFINITY; cnt[t] = 0; }
    csl[t] = cs[t]; csl[t + 256] = cs[t + 256];

    // A fragments: rows wv*16+m, k = quad*8+j (chunk0: k 0..31, chunk1: 32..63)
    const float* xrow = x + (size_t)(rowBlk0 + wv * 16 + m) * DDIM + quad * 8;
    U4S8 axh0, axh1, axl0, axl1;
    {
        float4 a0 = *(const float4*)(xrow);
        float4 b0 = *(const float4*)(xrow + 4);
        float4 a1 = *(const float4*)(xrow + 32);
        float4 b1 = *(const float4*)(xrow + 36);
        pack8(a0, b0, axh0.u, axl0.u);
        pack8(a1, b1, axh1.u, axl1.u);
    }

    for (int p = 0; p < 2; ++p) {
        // Stage B (256 codes, hi+lo), XOR-swizzled 16B granules.
#pragma unroll
        for (int i = 0; i < 8; ++i) {
            int g  = t + i * 256;                 // 0..2047
            int nl = g >> 3, c = g & 7;
            int d  = (nl << 3) | (c ^ (nl & 7));
            chL[d] = ((const uint4*)cbh)[p * 2048 + g];
            clL[d] = ((const uint4*)cbl)[p * 2048 + g];
        }
        __syncthreads();

        const int rbase = wv * 16 + quad * 4;     // score row base (local)
#pragma unroll 2
        for (int tt = 0; tt < 16; ++tt) {
            int nl = tt * 16 + m;
            int g0 = (nl << 3) | ( quad      ^ (nl & 7));
            int g1 = (nl << 3) | ((4 + quad) ^ (nl & 7));
            U4S8 bh0, bh1, bl0, bl1;
            bh0.u = chL[g0]; bh1.u = chL[g1];
            bl0.u = clL[g0]; bl1.u = clL[g1];
            f32x4 acc = {0.f, 0.f, 0.f, 0.f};
            acc = __builtin_amdgcn_mfma_f32_16x16x32_bf16(axh0.s, bh0.s, acc, 0, 0, 0);
            acc = __builtin_amdgcn_mfma_f32_16x16x32_bf16(axh1.s, bh1.s, acc, 0, 0, 0);
            acc = __builtin_amdgcn_mfma_f32_16x16x32_bf16(axl0.s, bh0.s, acc, 0, 0, 0);
            acc = __builtin_amdgcn_mfma_f32_16x16x32_bf16(axl1.s, bh1.s, acc, 0, 0, 0);
            acc = __builtin_amdgcn_mfma_f32_16x16x32_bf16(axh0.s, bl0.s, acc, 0, 0, 0);
            acc = __builtin_amdgcn_mfma_f32_16x16x32_bf16(axh1.s, bl1.s, acc, 0, 0, 0);
            float csn = csl[p * 256 + nl];
#pragma unroll
            for (int s = 0; s < 4; ++s)
                sc[(rbase + s) * 257 + nl] = __fmaf_rn(-2.0f, acc[s], csn);
        }
        __syncthreads();

        // Rescan 1: per-segment minima.
        {
            int row = t & 63, seg = t >> 6;
            const float* srow = sc + row * 257 + seg * 64;
            float mn = INFINITY;
            for (int i = 0; i < 64; ++i) mn = fminf(mn, srow[i]);
            segmn[seg * 64 + row] = mn;
        }
        __syncthreads();
        if (t < 64) {
            float mr = fminf(fminf(segmn[t], segmn[64 + t]),
                             fminf(segmn[128 + t], segmn[192 + t]));
            rowmn[t] = fminf(rowmn[t], mr);
        }
        __syncthreads();
        // Rescan 2: collect candidates within running-min + MARGIN (superset
        // of final-min + MARGIN since rowmn only decreases).
        {
            int row = t & 63, seg = t >> 6;
            float thr = rowmn[row] + MARGIN;
            const float* srow = sc + row * 257 + seg * 64;
            for (int i = 0; i < 64; ++i) {
                float s = srow[i];
                if (s <= thr) {
                    int pos = atomicAdd(&cnt[row], 1);
                    if (pos < 8) {
                        lstk[row * 8 + pos] = p * 256 + seg * 64 + i;
                        lsts[row * 8 + pos] = s;
                    }
                }
            }
        }
        __syncthreads();
    }

    // Final selection per row.
    if (t < 64) {
        int row = t;
        int c = cnt[row];
        int kb;
        if (c <= 8) {
            float thr = rowmn[row] + MARGIN;
            int nc = 0, cand[8];
            for (int i = 0; i < c; ++i)
                if (lsts[row * 8 + i] <= thr) cand[nc++] = lstk[row * 8 + i];
            if (nc == 1) kb = cand[0];
            else         kb = exact_select(x, cb, csl, rowBlk0 + row, cand, nc);
        } else {
            kb = exact_select_all(x, cb, csl, rowBlk0 + row);
        }
        win[row] = kb;
        out[2 * ND + (size_t)(rowBlk0 + row)] = (float)kb;
    }
    __syncthreads();

    // Epilogue: z_q = z_q_bar = codebook[win], fully coalesced block writes.
#pragma unroll
    for (int i = 0; i < 4; ++i) {
        int g   = t + i * 256;                // 0..1023 float4-granules
        int row = g >> 4, cc = g & 15;
        int kb  = win[row];
        float4 v = *(const float4*)(cb + (size_t)kb * DDIM + cc * 4);
        size_t gr = (size_t)(rowBlk0 + row) * DDIM + (size_t)cc * 4;
        *(float4*)(out + gr) = v;
        *(float4*)(out + ND + gr) = v;
    }
}

extern "C" void kernel_launch(void* const* d_in, const int* in_sizes, int n_in,
                              void* d_out, int out_size, void* d_ws, size_t ws_size,
                              hipStream_t stream) {
    const float* z  = (const float*)d_in[0];   // [N, D] fp32
    const float* cb = (const float*)d_in[1];   // [K, D] fp32
    float* out = (float*)d_out;                // [N*D | N*D | N] fp32
    float* cs           = (float*)d_ws;                               // 512 f32
    unsigned short* cbh = (unsigned short*)((char*)d_ws + 2048);      // 64 KB
    unsigned short* cbl = (unsigned short*)((char*)d_ws + 2048 + 65536);

    (void)hipFuncSetAttribute((const void*)vq_main,
                              hipFuncAttributeMaxDynamicSharedMemorySize,
                              SMEM_BYTES);
    vq_prep<<<2, 256, 0, stream>>>(cb, cs, cbh, cbl);
    vq_main<<<NROWS / MBLK, 256, SMEM_BYTES, stream>>>(z, cb, cs, cbh, cbl, out);
}